// Round 4
// baseline (337.719 us; speedup 1.0000x reference)
//
#include <hip/hip_runtime.h>
#include <math.h>

// Problem constants
#define CC 3
#define HH 1280
#define WW 720
#define BSZ 20
#define NHB 64
#define NWB 36
#define NBLK (NHB*NWB)          // 2304
#define OUT_IMG (3*5120*2880)   // 44236800

// LDS layouts for the two block roles (union'd into one buffer).
struct LightSm {
  float in_s[3][22][24];    // zero-padded block, rows 24 for float4 reads (6336 B)
  float w4[12*27*4];        // [ocg=(c*4+r1)][k=ic*9+ky*3+kx][r2]  (5184 B)
  float bias[48];
};
struct GateSm {
  float ins[3][26][28];     // clamped input patch (edge pad baked in)   8736 B
  float w1p[4*27*4];        // [ocg][k][r2] for conv1 (16 oc = 4 grp x4) 1728 B
  float w2p[8*16*3*4];      // [oc2][ic][ky][kx(0..2)+pad]               1536 B
  float w3s[200];
  float x1s[16][12][14];    // post-pool conv1 patch, stride 14 (even)  10752 B
  float b1s[16];
  float b2s[8];
  float b3s_;
  float red[256];
};
#define SM_BYTES (sizeof(GateSm) > sizeof(LightSm) ? sizeof(GateSm) : sizeof(LightSm))

// ---------------------------------------------------------------------------
// Fused single-dispatch kernel: even blocks = light expert, odd = gate CNN.
// mask = sigmoid(..) > 1.0 is always False -> complex expert is dead code.
// ---------------------------------------------------------------------------
__global__ __launch_bounds__(256) void fused_kernel(
    const float* __restrict__ inp,
    const float* __restrict__ w1, const float* __restrict__ b1,
    const float* __restrict__ w2, const float* __restrict__ b2,
    const float* __restrict__ w3, const float* __restrict__ b3,
    const float* __restrict__ wl, const float* __restrict__ bl,
    float* __restrict__ out, float* __restrict__ cv) {
  __shared__ __align__(16) char smraw[SM_BYTES];
  const int tid = threadIdx.x;
  const int l = blockIdx.x >> 1;

  if ((blockIdx.x & 1) == 0) {
    // ============================ LIGHT EXPERT ============================
    LightSm& sm = *(LightSm*)smraw;
    const int bi = l / NWB, bj = l % NWB;

    for (int i = tid; i < 3*22*24; i += 256) ((float*)sm.in_s)[i] = 0.0f;
    // repack weights: oc = c*16+r1*4+r2 -> group ocg=oc>>2, slot r2=oc&3
    for (int i = tid; i < 48*27; i += 256) {
      int oc = i / 27, k = i - oc*27;
      sm.w4[((oc >> 2)*27 + k)*4 + (oc & 3)] = wl[i];
    }
    if (tid < 48) sm.bias[tid] = bl[tid];
    __syncthreads();
    // stage 20x20x3 block; float4 global loads (720 and 20*bj are mult of 4)
    for (int i = tid; i < 300; i += 256) {
      int x4 = i % 5; int r = (i / 5) % 20; int c = i / 100;
      const float4 v = *(const float4*)&inp[(c*HH + bi*BSZ + r)*WW + bj*BSZ + 4*x4];
      float* dst = &sm.in_s[c][r+1][1 + 4*x4];
      dst[0] = v.x; dst[1] = v.y; dst[2] = v.z; dst[3] = v.w;
    }
    __syncthreads();

    if (tid < 240) {
      const int ocg = tid / 20, h = tid % 20;   // ocg = c*4+r1
      const float4* wq = (const float4*)&sm.w4[ocg*27*4];
      float b0 = sm.bias[ocg*4+0], b1v = sm.bias[ocg*4+1];
      float b2v = sm.bias[ocg*4+2], b3v = sm.bias[ocg*4+3];
      float acc0[20], acc1[20], acc2[20], acc3[20];
      #pragma unroll
      for (int w = 0; w < 20; ++w) { acc0[w]=b0; acc1[w]=b1v; acc2[w]=b2v; acc3[w]=b3v; }

      #pragma unroll
      for (int ic = 0; ic < 3; ++ic)
        #pragma unroll
        for (int ky = 0; ky < 3; ++ky) {
          const float* row = &sm.in_s[ic][h + ky][0];
          float r[24];
          #pragma unroll
          for (int j = 0; j < 6; ++j) {
            float4 v = ((const float4*)row)[j];   // ds_read_b128
            r[j*4+0]=v.x; r[j*4+1]=v.y; r[j*4+2]=v.z; r[j*4+3]=v.w;
          }
          float4 wa = wq[ic*9 + ky*3 + 0];   // 4 ocs' weights for kx=0
          float4 wb = wq[ic*9 + ky*3 + 1];
          float4 wc = wq[ic*9 + ky*3 + 2];
          #pragma unroll
          for (int w = 0; w < 20; ++w) {
            float x0 = r[w], x1 = r[w+1], x2 = r[w+2];
            acc0[w] += x0*wa.x + x1*wb.x + x2*wc.x;
            acc1[w] += x0*wa.y + x1*wb.y + x2*wc.y;
            acc2[w] += x0*wa.z + x1*wb.z + x2*wc.z;
            acc3[w] += x0*wa.w + x1*wb.w + x2*wc.w;
          }
        }

      // pixel_shuffle: out[c][4h+r1][4w+r2]; r2=0..3 are the float4 lanes
      const int c = ocg >> 2, r1 = ocg & 3;
      float4* obase = (float4*)&out[(c*5120 + bi*80 + 4*h + r1)*2880 + bj*80];
      #pragma unroll
      for (int w = 0; w < 20; ++w) {
        float4 v;
        v.x = fminf(fmaxf(acc0[w], 0.0f), 0.6f) + 0.4f;
        v.y = fminf(fmaxf(acc1[w], 0.0f), 0.6f) + 0.4f;
        v.z = fminf(fmaxf(acc2[w], 0.0f), 0.6f) + 0.4f;
        v.w = fminf(fmaxf(acc3[w], 0.0f), 0.6f) + 0.4f;
        obase[w] = v;
      }
    }
  } else {
    // ============================= GATE CNN ==============================
    GateSm& sm = *(GateSm*)smraw;
    const int oy = l / NWB, ox = l % NWB;

    for (int i = tid; i < 16*27; i += 256) {
      int oc = i / 27, k = i - oc*27;
      sm.w1p[((oc >> 2)*27 + k)*4 + (oc & 3)] = w1[i];
    }
    for (int i = tid; i < 8*16*9; i += 256) {
      int oc2 = i / 144; int r = i - oc2*144; int ic = r / 9;
      int ky = (r % 9) / 3; int kx = r % 3;
      sm.w2p[((oc2*16 + ic)*3 + ky)*4 + kx] = w2[i];
    }
    for (int i = tid; i < 200; i += 256) sm.w3s[i] = w3[i];
    if (tid < 16) sm.b1s[tid] = b1[tid];
    if (tid < 8)  sm.b2s[tid] = b2[tid];
    if (tid == 0) sm.b3s_ = b3[0];

    // input patch rows/cols [20*o-3, 20*o+23), clamped (both edge_pads baked in)
    for (int i = tid; i < 3*26*28; i += 256) {
      int b = i % 28; int a = (i / 28) % 26; int ic = i / (26*28);
      int gy = 20*oy - 3 + a; gy = gy < 0 ? 0 : (gy > HH-1 ? HH-1 : gy);
      int gx = 20*ox - 3 + b; gx = gx < 0 ? 0 : (gx > WW-1 ? WW-1 : gx);
      sm.ins[ic][a][b] = inp[(ic*HH + gy)*WW + gx];
    }
    __syncthreads();

    // ---- stage A: conv1 + tanh + maxpool, 4-oc blocked. 576 tasks.
    for (int t = tid; t < 576; t += 256) {
      const int ocg = t / 144; const int pos = t - ocg*144;
      const int ly = pos / 12, lx = pos - ly*12;
      int y1 = 10*oy - 1 + ly; y1 = y1 < 0 ? 0 : (y1 > 639 ? 639 : y1);
      int x1 = 10*ox - 1 + lx; x1 = x1 < 0 ? 0 : (x1 > 359 ? 359 : x1);
      const int ry = 2*y1 + 2 - 20*oy;   // even, in [0,22]
      const int rx = 2*x1 + 2 - 20*ox;   // even
      float p[3][4][4];
      #pragma unroll
      for (int ic = 0; ic < 3; ++ic)
        #pragma unroll
        for (int d = 0; d < 4; ++d) {
          float2 u = *(const float2*)&sm.ins[ic][ry+d][rx];     // 8B-aligned
          float2 v = *(const float2*)&sm.ins[ic][ry+d][rx+2];
          p[ic][d][0]=u.x; p[ic][d][1]=u.y; p[ic][d][2]=v.x; p[ic][d][3]=v.y;
        }
      const float4* wv = (const float4*)&sm.w1p[ocg*27*4];
      float acc[4][4];   // [window][r2]
      #pragma unroll
      for (int win = 0; win < 4; ++win)
        #pragma unroll
        for (int r = 0; r < 4; ++r) acc[win][r] = sm.b1s[ocg*4 + r];
      #pragma unroll
      for (int ic = 0; ic < 3; ++ic)
        #pragma unroll
        for (int ky = 0; ky < 3; ++ky)
          #pragma unroll
          for (int kx = 0; kx < 3; ++kx) {
            float4 wq = wv[ic*9 + ky*3 + kx];
            #pragma unroll
            for (int sy = 0; sy < 2; ++sy)
              #pragma unroll
              for (int sx = 0; sx < 2; ++sx) {
                float pv = p[ic][sy+ky][sx+kx];
                acc[sy*2+sx][0] += pv*wq.x;
                acc[sy*2+sx][1] += pv*wq.y;
                acc[sy*2+sx][2] += pv*wq.z;
                acc[sy*2+sx][3] += pv*wq.w;
              }
          }
      #pragma unroll
      for (int r = 0; r < 4; ++r) {
        float m = fmaxf(fmaxf(acc[0][r], acc[1][r]), fmaxf(acc[2][r], acc[3][r]));
        sm.x1s[ocg*4 + r][ly][lx] = tanhf(m);   // maxpool(tanh)==tanh(maxpool)
      }
    }
    __syncthreads();

    // ---- stage B: conv2 + maxpool at the 5x5 window; product with w3
    float prod = 0.0f;
    if (tid < 200) {
      const int oc2 = tid / 25; const int rem = tid - oc2*25;
      const int j = rem / 5, i5 = rem - j*5;
      float a00 = sm.b2s[oc2], a01 = a00, a10 = a00, a11 = a00;
      for (int ic = 0; ic < 16; ++ic) {
        float p[4][4];
        #pragma unroll
        for (int d = 0; d < 4; ++d) {
          float2 u = *(const float2*)&sm.x1s[ic][2*j + d][2*i5];     // stride 14: even
          float2 v = *(const float2*)&sm.x1s[ic][2*j + d][2*i5 + 2];
          p[d][0]=u.x; p[d][1]=u.y; p[d][2]=v.x; p[d][3]=v.y;
        }
        #pragma unroll
        for (int ky = 0; ky < 3; ++ky) {
          float4 wq = *(const float4*)&sm.w2p[((oc2*16 + ic)*3 + ky)*4];
          a00 += p[ky  ][0]*wq.x + p[ky  ][1]*wq.y + p[ky  ][2]*wq.z;
          a01 += p[ky  ][1]*wq.x + p[ky  ][2]*wq.y + p[ky  ][3]*wq.z;
          a10 += p[ky+1][0]*wq.x + p[ky+1][1]*wq.y + p[ky+1][2]*wq.z;
          a11 += p[ky+1][1]*wq.x + p[ky+1][2]*wq.y + p[ky+1][3]*wq.z;
        }
      }
      float x2 = fmaxf(fmaxf(a00, a01), fmaxf(a10, a11));
      prod = x2 * sm.w3s[tid];
    }
    sm.red[tid] = prod;
    __syncthreads();

    if (tid < 64) {
      float s = sm.red[tid] + sm.red[tid+64] + sm.red[tid+128] + sm.red[tid+192];
      #pragma unroll
      for (int off = 32; off > 0; off >>= 1) s += __shfl_down(s, off);
      if (tid == 0)
        cv[l] = 1.0f / (1.0f + expf(-(s + sm.b3s_)));
    }
  }
}

// ---------------------------------------------------------------------------
extern "C" void kernel_launch(void* const* d_in, const int* in_sizes, int n_in,
                              void* d_out, int out_size, void* d_ws, size_t ws_size,
                              hipStream_t stream) {
  const float* inp = (const float*)d_in[0];
  const float* w1  = (const float*)d_in[1];
  const float* b1  = (const float*)d_in[2];
  const float* w2  = (const float*)d_in[3];
  const float* b2  = (const float*)d_in[4];
  const float* w3  = (const float*)d_in[5];
  const float* b3  = (const float*)d_in[6];
  const float* wl  = (const float*)d_in[7];
  const float* bl  = (const float*)d_in[8];
  // d_in[9..14] = wc1..bc3: dead (gate sigmoid <= 1 -> mask always False)

  float* out = (float*)d_out;

  hipLaunchKernelGGL(fused_kernel, dim3(2*NBLK), dim3(256), 0, stream,
                     inp, w1, b1, w2, b2, w3, b3, wl, bl, out, out + OUT_IMG);
}